// Round 9
// baseline (113.656 us; speedup 1.0000x reference)
//
#include <hip/hip_runtime.h>
#include <math.h>

#define HID_DIM  512
#define HIDH_DIM 256
#define ZBLOCKS  125
#define UBLOCKS  128   // u-fold blocks: one wave per output k
#define JC       512   // clash j-tile (LDS-staged)

// ---------------------------------------------------------------------------
__device__ __forceinline__ float dot4(float4 a, float4 b) {
    return a.x * b.x + a.y * b.y + a.z * b.z + a.w * b.w;
}

// ---------------------------------------------------------------------------
// Fused prep:
//   [0,125)      : grid-stride zero of bond_corr
//   125          : edge-dtype probe + cvals reduction
//   [126,254)    : u-fold, one wave per k (coalesced float4 + butterfly)
//   [254,254+GB) : xg (SoA) gather
//   [..., +MB)   : mask/gpos via binary search over sorted gen_idx
__global__ __launch_bounds__(256) void prep_kernel(
        const unsigned int* __restrict__ ew,
        const float* __restrict__ Wp,  const float* __restrict__ bp,
        const float* __restrict__ wb,  const float* __restrict__ bb,
        const float* __restrict__ wv,  const float* __restrict__ bv,
        const int* __restrict__ gen_idx, const float* __restrict__ x_t,
        float4* __restrict__ zbase, int zcount,
        float* __restrict__ u_bond, float* __restrict__ u_val,
        float* __restrict__ cvals, int* __restrict__ flag,
        float* __restrict__ xgx, float* __restrict__ xgy, float* __restrict__ xgz,
        unsigned char* __restrict__ mask, int* __restrict__ gpos,
        int n, int G, int GB) {
    int b = blockIdx.x, t = threadIdx.x;
    if (b < ZBLOCKS) {
        const float4 z = make_float4(0.f, 0.f, 0.f, 0.f);
        for (int i = b * 256 + t; i < zcount; i += ZBLOCKS * 256) zbase[i] = z;
    } else if (b == ZBLOCKS) {
        if (t < 64) {  // wave 0: int64-vs-int32 edge layout probe
            unsigned int v = ew[2 * t + 1];
            unsigned long long bl = __ballot(v == 0u);
            if (t == 0) flag[0] = (bl == 0xFFFFFFFFFFFFFFFFULL) ? 1 : 0;
        }
        __shared__ float s1[256], s2[256];
        float p1 = (t < HIDH_DIM) ? bp[t] * wb[t] : 0.f;
        float p2 = (t < HIDH_DIM) ? bp[t] * wv[t] : 0.f;
        s1[t] = p1; s2[t] = p2;
        __syncthreads();
        for (int s = 128; s > 0; s >>= 1) {
            if (t < s) { s1[t] += s1[t + s]; s2[t] += s2[t + s]; }
            __syncthreads();
        }
        if (t == 0) { cvals[0] = s1[0] + bb[0]; cvals[1] = s2[0] + bv[0]; }
    } else if (b < ZBLOCKS + 1 + UBLOCKS) {
        // one wave per output k: lanes cover the 256-wide dot coalesced
        int w = t >> 6, lane = t & 63;
        int k = (b - ZBLOCKS - 1) * 4 + w;
        if (k < HID_DIM) {
            const float* wrow = Wp + (size_t)k * HIDH_DIM;
            float4 wr = *reinterpret_cast<const float4*>(wrow + lane * 4);
            float4 vb = *reinterpret_cast<const float4*>(wb + lane * 4);
            float4 vv = *reinterpret_cast<const float4*>(wv + lane * 4);
            float ub = dot4(wr, vb);
            float uv = dot4(wr, vv);
            #pragma unroll
            for (int off = 32; off > 0; off >>= 1) {
                ub += __shfl_down(ub, off, 64);
                uv += __shfl_down(uv, off, 64);
            }
            if (lane == 0) { u_bond[k] = ub; u_val[k] = uv; }
        }
    } else if (b < ZBLOCKS + 1 + UBLOCKS + GB) {
        int g = (b - ZBLOCKS - 1 - UBLOCKS) * 256 + t;
        if (g < G) {
            int idx = gen_idx[g];
            xgx[g] = x_t[3 * idx + 0];
            xgy[g] = x_t[3 * idx + 1];
            xgz[g] = x_t[3 * idx + 2];
        }
    } else {
        int base = ((b - ZBLOCKS - 1 - UBLOCKS - GB) * 256 + t) * 8;
        for (int k = 0; k < 8; ++k) {
            int i = base + k;
            if (i >= n) break;
            int lo = 0, hi = G - 1, g = -1;
            while (lo <= hi) {
                int mid = (lo + hi) >> 1;
                int v = gen_idx[mid];
                if (v == i) { g = mid; break; }
                if (v < i) lo = mid + 1; else hi = mid - 1;
            }
            mask[i] = (g >= 0) ? 1 : 0;
            if (g >= 0) gpos[i] = g;
        }
    }
}

// ---------------------------------------------------------------------------
// Mega kernel v5 — striped roles, stripe of 9: {0..3}->gate, {4..7}->bond,
// {8}->clash. launch_bounds(256,4): VGPR cap 128 so gate keeps 8 float4
// loads in flight (8 KB/wave).
__global__ __launch_bounds__(256, 4) void mega_kernel(
        const float* __restrict__ H,
        const float* __restrict__ u_bond, const float* __restrict__ u_val,
        const float* __restrict__ cvals,
        const unsigned int* __restrict__ ew, const int* __restrict__ flag_p,
        const float* __restrict__ x_t, const unsigned char* __restrict__ mask,
        const float* __restrict__ xgx, const float* __restrict__ xgy,
        const float* __restrict__ xgz,
        float* __restrict__ bond_corr,
        float4* __restrict__ partials,
        float* __restrict__ bond_w, float* __restrict__ clash_w,
        int n, int E, int G, int NBG, int NBB, int NBC, int CXB) {
    __shared__ __align__(16) float sx[JC];
    __shared__ __align__(16) float sy[JC];
    __shared__ __align__(16) float sz[JC];
    int b = blockIdx.x, t = threadIdx.x;
    int stripe = b / 9, role = b - stripe * 9;

    if (role < 4) {
        // ---- gates: 32 rows/block, 8 rows/wave, 4 rows/iter, 8 loads deep ----
        int bb = stripe * 4 + role;
        if (bb >= NBG) return;
        int w = t >> 6, lane = t & 63;
        int row0 = bb * 32 + w * 8;
        int o0 = lane * 4, o1 = 256 + lane * 4;
        float4 ub0 = *reinterpret_cast<const float4*>(u_bond + o0);
        float4 ub1 = *reinterpret_cast<const float4*>(u_bond + o1);
        float4 uv0 = *reinterpret_cast<const float4*>(u_val + o0);
        float4 uv1 = *reinterpret_cast<const float4*>(u_val + o1);
        float c0 = cvals[0], c1 = cvals[1];
        #pragma unroll
        for (int r = 0; r < 8; r += 4) {
            int ra = row0 + r;
            bool v0 = (ra < n), v1 = (ra + 1 < n), v2 = (ra + 2 < n), v3 = (ra + 3 < n);
            const float* h0 = H + (size_t)(v0 ? ra     : 0) * HID_DIM;
            const float* h1 = H + (size_t)(v1 ? ra + 1 : 0) * HID_DIM;
            const float* h2 = H + (size_t)(v2 ? ra + 2 : 0) * HID_DIM;
            const float* h3 = H + (size_t)(v3 ? ra + 3 : 0) * HID_DIM;
            // 8 independent 16B loads in flight before any consumption
            float4 a0 = *reinterpret_cast<const float4*>(h0 + o0);
            float4 a1 = *reinterpret_cast<const float4*>(h0 + o1);
            float4 b0 = *reinterpret_cast<const float4*>(h1 + o0);
            float4 b1 = *reinterpret_cast<const float4*>(h1 + o1);
            float4 e0 = *reinterpret_cast<const float4*>(h2 + o0);
            float4 e1 = *reinterpret_cast<const float4*>(h2 + o1);
            float4 d0 = *reinterpret_cast<const float4*>(h3 + o0);
            float4 d1 = *reinterpret_cast<const float4*>(h3 + o1);
            float sb0 = dot4(a0, ub0) + dot4(a1, ub1);
            float sv0 = dot4(a0, uv0) + dot4(a1, uv1);
            float sb1 = dot4(b0, ub0) + dot4(b1, ub1);
            float sv1 = dot4(b0, uv0) + dot4(b1, uv1);
            float sb2 = dot4(e0, ub0) + dot4(e1, ub1);
            float sv2 = dot4(e0, uv0) + dot4(e1, uv1);
            float sb3 = dot4(d0, ub0) + dot4(d1, ub1);
            float sv3 = dot4(d0, uv0) + dot4(d1, uv1);
            #pragma unroll
            for (int off = 32; off > 0; off >>= 1) {
                sb0 += __shfl_down(sb0, off, 64);
                sv0 += __shfl_down(sv0, off, 64);
                sb1 += __shfl_down(sb1, off, 64);
                sv1 += __shfl_down(sv1, off, 64);
                sb2 += __shfl_down(sb2, off, 64);
                sv2 += __shfl_down(sv2, off, 64);
                sb3 += __shfl_down(sb3, off, 64);
                sv3 += __shfl_down(sv3, off, 64);
            }
            if (lane == 0) {
                if (v0) {
                    bond_w [ra]     = 1.f / (1.f + expf(-(sb0 + c0)));
                    clash_w[ra]     = 1.f / (1.f + expf(-(sv0 + c1)));
                }
                if (v1) {
                    bond_w [ra + 1] = 1.f / (1.f + expf(-(sb1 + c0)));
                    clash_w[ra + 1] = 1.f / (1.f + expf(-(sv1 + c1)));
                }
                if (v2) {
                    bond_w [ra + 2] = 1.f / (1.f + expf(-(sb2 + c0)));
                    clash_w[ra + 2] = 1.f / (1.f + expf(-(sv2 + c1)));
                }
                if (v3) {
                    bond_w [ra + 3] = 1.f / (1.f + expf(-(sb3 + c0)));
                    clash_w[ra + 3] = 1.f / (1.f + expf(-(sv3 + c1)));
                }
            }
        }
    } else if (role < 8) {
        // ---- bond scatter ----
        int eb = stripe * 4 + (role - 4);
        if (eb >= NBB) return;
        int e = eb * 256 + t;
        if (e >= E) return;
        int f = flag_p[0];
        int row, col;
        if (f) {  // int64 layout: low words at even word indices
            row = (int)ew[2 * (size_t)e];
            col = (int)ew[2 * ((size_t)E + e)];
        } else {  // int32 layout
            row = (int)ew[e];
            col = (int)ew[(size_t)E + e];
        }
        if ((unsigned)row >= (unsigned)n || (unsigned)col >= (unsigned)n) return;
        if (!(mask[row] | mask[col])) return;
        float dx = x_t[3 * row + 0] - x_t[3 * col + 0];
        float dy = x_t[3 * row + 1] - x_t[3 * col + 1];
        float dz = x_t[3 * row + 2] - x_t[3 * col + 2];
        float d2 = dx * dx + dy * dy + dz * dz;
        float dist = sqrtf(fmaxf(d2, 1e-24f)) + 1e-8f;
        float s = (dist - 1.5f) / (dist * dist);
        float fx = s * dx, fy = s * dy, fz = s * dz;
        atomicAdd(&bond_corr[3 * row + 0],  fx);
        atomicAdd(&bond_corr[3 * row + 1],  fy);
        atomicAdd(&bond_corr[3 * row + 2],  fz);
        atomicAdd(&bond_corr[3 * col + 0], -fx);
        atomicAdd(&bond_corr[3 * col + 1], -fy);
        atomicAdd(&bond_corr[3 * col + 2], -fz);
    } else {
        // ---- clash: branchless; JC=512 j-tile; float4 partial per (yc,i) ----
        int b2 = stripe;
        if (b2 >= NBC) return;
        int yc = b2 / CXB;
        int i  = (b2 - yc * CXB) * 256 + t;
        int j0 = yc * JC;
        {
            int ja = j0 + t, jb = j0 + t + 256;
            sx[t]       = (ja < G) ? xgx[ja] : 1e30f;
            sy[t]       = (ja < G) ? xgy[ja] : 1e30f;
            sz[t]       = (ja < G) ? xgz[ja] : 1e30f;
            sx[t + 256] = (jb < G) ? xgx[jb] : 1e30f;
            sy[t + 256] = (jb < G) ? xgy[jb] : 1e30f;
            sz[t + 256] = (jb < G) ? xgz[jb] : 1e30f;
        }
        __syncthreads();
        if (i >= G) return;
        float xi = xgx[i], yi = xgy[i], zi = xgz[i];
        float csum = 0.f, cx = 0.f, cy = 0.f, cz = 0.f;
#define PROC(XS, YS, ZS) do {                                           \
            float dx = xi - (XS), dy = yi - (YS), dz = zi - (ZS);       \
            float d2 = fmaf(dx, dx, fmaf(dy, dy, dz * dz));             \
            float rm = __builtin_amdgcn_rsqf(d2);                       \
            float coef = fmaxf(fmaf(rm, rm, -rm), 0.0f);                \
            csum += coef;                                               \
            cx = fmaf(coef, (XS), cx);                                  \
            cy = fmaf(coef, (YS), cy);                                  \
            cz = fmaf(coef, (ZS), cz);                                  \
        } while (0)
        #pragma unroll 4
        for (int tt = 0; tt < JC; tt += 4) {
            float4 ax = *reinterpret_cast<const float4*>(&sx[tt]);
            float4 ay = *reinterpret_cast<const float4*>(&sy[tt]);
            float4 az = *reinterpret_cast<const float4*>(&sz[tt]);
            PROC(ax.x, ay.x, az.x);
            PROC(ax.y, ay.y, az.y);
            PROC(ax.z, ay.z, az.z);
            PROC(ax.w, ay.w, az.w);
        }
#undef PROC
        partials[(size_t)yc * G + i] = make_float4(csum, cx, cy, cz);
    }
}

// ---------------------------------------------------------------------------
// out = v_x - 0.1*bond_w*bond_corr - [mask] 0.05*clash_w*(xg*S - V),
// S,V summed from NYC=16 coalesced float4 partials.
__global__ void final_kernel(const float* __restrict__ v_x,
                             const float* __restrict__ bond_w,
                             const float* __restrict__ clash_w,
                             const float* __restrict__ bond_corr,
                             const unsigned char* __restrict__ mask,
                             const int* __restrict__ gpos,
                             const float* __restrict__ xgx,
                             const float* __restrict__ xgy,
                             const float* __restrict__ xgz,
                             const float4* __restrict__ partials,
                             float* __restrict__ out, int n, int G, int NYC) {
    int i = blockIdx.x * blockDim.x + threadIdx.x;
    if (i >= n) return;
    float bw = 0.1f * bond_w[i];
    float ox = v_x[3 * i + 0] - bw * bond_corr[3 * i + 0];
    float oy = v_x[3 * i + 1] - bw * bond_corr[3 * i + 1];
    float oz = v_x[3 * i + 2] - bw * bond_corr[3 * i + 2];
    if (mask[i]) {
        int g = gpos[i];
        float s = 0.f, vx = 0.f, vy = 0.f, vz = 0.f;
        for (int yc = 0; yc < NYC; ++yc) {
            float4 p = partials[(size_t)yc * G + g];
            s += p.x; vx += p.y; vy += p.z; vz += p.w;
        }
        float cw = 0.05f * clash_w[i];
        ox -= cw * (xgx[g] * s - vx);
        oy -= cw * (xgy[g] * s - vy);
        oz -= cw * (xgz[g] * s - vz);
    }
    out[3 * i + 0] = ox;
    out[3 * i + 1] = oy;
    out[3 * i + 2] = oz;
}

// ---------------------------------------------------------------------------
extern "C" void kernel_launch(void* const* d_in, const int* in_sizes, int n_in,
                              void* d_out, int out_size, void* d_ws, size_t ws_size,
                              hipStream_t stream) {
    const float* v_x_raw = (const float*)d_in[0];
    const float* H       = (const float*)d_in[1];
    const float* x_t     = (const float*)d_in[2];
    const unsigned int* edges_w = (const unsigned int*)d_in[3];
    // d_in[4] = gen_mask (bool) — intentionally unused; rebuilt from gen_idx.
    const int* gen_idx   = (const int*)d_in[5];
    const float* W_proj  = (const float*)d_in[6];
    const float* b_proj  = (const float*)d_in[7];
    const float* w_bond  = (const float*)d_in[8];
    const float* b_bond  = (const float*)d_in[9];
    const float* w_val   = (const float*)d_in[10];
    const float* b_val   = (const float*)d_in[11];

    const int n = in_sizes[0] / 3;
    const int E = in_sizes[3] / 2;
    const int G = in_sizes[5];
    const int GB  = (G + 255) / 256;
    const int NYC = (G + JC - 1) / JC;   // clash y-chunks (16)

    char* ws = (char*)d_ws;
    // --- zeroed region (bond_corr only) ---
    float* bond_corr = (float*)(ws);
    size_t zbytes = (size_t)n * 12;
    size_t off = (zbytes + 15) & ~(size_t)15;
    int zcount = (int)(off / 16);
    // --- write-every-launch region ---
    unsigned char* mask = (unsigned char*)(ws + off); off += ((size_t)n + 15) & ~(size_t)15;
    int*   gpos    = (int*)(ws + off);                off += (size_t)n * 4;
    float* bond_w  = (float*)(ws + off);              off += (size_t)n * 4;
    float* clash_w = (float*)(ws + off);              off += (size_t)n * 4;
    float* u_bond  = (float*)(ws + off);              off += HID_DIM * 4;
    float* u_val   = (float*)(ws + off);              off += HID_DIM * 4;
    float* cvals   = (float*)(ws + off);              off += 16;
    int*   flag    = (int*)(ws + off);                off += 16;
    float* xgx     = (float*)(ws + off);              off += (size_t)G * 4;
    float* xgy     = (float*)(ws + off);              off += (size_t)G * 4;
    float* xgz     = (float*)(ws + off);              off += (size_t)G * 4;
    float4* partials = (float4*)(ws + off);           off += (size_t)NYC * G * 16;

    const int MB  = (n + 2047) / 2048;   // mask/gpos blocks (8 idx/thread)
    const int CXB = GB;                   // clash x-blocks
    const int NBC = CXB * NYC;            // clash blocks (512)
    const int NBG = (n + 31) / 32;        // gate blocks (2048)
    const int NBB = (E + 255) / 256;      // bond blocks (2048)

    // stripes of 9: 4 gate + 4 bond + 1 clash
    int S = (NBG + 3) / 4;
    if ((NBB + 3) / 4 > S) S = (NBB + 3) / 4;
    if (NBC > S) S = NBC;

    prep_kernel<<<ZBLOCKS + 1 + UBLOCKS + GB + MB, 256, 0, stream>>>(
        edges_w, W_proj, b_proj, w_bond, b_bond, w_val, b_val,
        gen_idx, x_t, (float4*)ws, zcount,
        u_bond, u_val, cvals, flag, xgx, xgy, xgz, mask, gpos, n, G, GB);

    mega_kernel<<<S * 9, 256, 0, stream>>>(
        H, u_bond, u_val, cvals, edges_w, flag, x_t, mask,
        xgx, xgy, xgz, bond_corr, partials, bond_w, clash_w,
        n, E, G, NBG, NBB, NBC, CXB);

    final_kernel<<<(n + 255) / 256, 256, 0, stream>>>(
        v_x_raw, bond_w, clash_w, bond_corr, mask, gpos,
        xgx, xgy, xgz, partials, (float*)d_out, n, G, NYC);
}

// Round 10
// 111.423 us; speedup vs baseline: 1.0200x; 1.0200x over previous
//
#include <hip/hip_runtime.h>
#include <math.h>

#define HID_DIM  512
#define HIDH_DIM 256
#define ZBLOCKS  125
#define UBLOCKS  128   // u-fold blocks: one wave per output k
#define JC       256   // clash j-tile (LDS-staged)

// ---------------------------------------------------------------------------
__device__ __forceinline__ float dot4(float4 a, float4 b) {
    return a.x * b.x + a.y * b.y + a.z * b.z + a.w * b.w;
}

// ---------------------------------------------------------------------------
// Fused prep:
//   [0,125)      : grid-stride zero of bond_corr
//   125          : edge-dtype probe + cvals reduction
//   [126,254)    : u-fold, one wave per k (coalesced float4 + butterfly)
//   [254,254+GB) : xg (SoA) gather
//   [..., +MB)   : mask/gpos via binary search over sorted gen_idx
__global__ __launch_bounds__(256) void prep_kernel(
        const unsigned int* __restrict__ ew,
        const float* __restrict__ Wp,  const float* __restrict__ bp,
        const float* __restrict__ wb,  const float* __restrict__ bb,
        const float* __restrict__ wv,  const float* __restrict__ bv,
        const int* __restrict__ gen_idx, const float* __restrict__ x_t,
        float4* __restrict__ zbase, int zcount,
        float* __restrict__ u_bond, float* __restrict__ u_val,
        float* __restrict__ cvals, int* __restrict__ flag,
        float* __restrict__ xgx, float* __restrict__ xgy, float* __restrict__ xgz,
        unsigned char* __restrict__ mask, int* __restrict__ gpos,
        int n, int G, int GB) {
    int b = blockIdx.x, t = threadIdx.x;
    if (b < ZBLOCKS) {
        const float4 z = make_float4(0.f, 0.f, 0.f, 0.f);
        for (int i = b * 256 + t; i < zcount; i += ZBLOCKS * 256) zbase[i] = z;
    } else if (b == ZBLOCKS) {
        if (t < 64) {  // wave 0: int64-vs-int32 edge layout probe
            unsigned int v = ew[2 * t + 1];
            unsigned long long bl = __ballot(v == 0u);
            if (t == 0) flag[0] = (bl == 0xFFFFFFFFFFFFFFFFULL) ? 1 : 0;
        }
        __shared__ float s1[256], s2[256];
        float p1 = (t < HIDH_DIM) ? bp[t] * wb[t] : 0.f;
        float p2 = (t < HIDH_DIM) ? bp[t] * wv[t] : 0.f;
        s1[t] = p1; s2[t] = p2;
        __syncthreads();
        for (int s = 128; s > 0; s >>= 1) {
            if (t < s) { s1[t] += s1[t + s]; s2[t] += s2[t + s]; }
            __syncthreads();
        }
        if (t == 0) { cvals[0] = s1[0] + bb[0]; cvals[1] = s2[0] + bv[0]; }
    } else if (b < ZBLOCKS + 1 + UBLOCKS) {
        // one wave per output k: lanes cover the 256-wide dot coalesced
        int w = t >> 6, lane = t & 63;
        int k = (b - ZBLOCKS - 1) * 4 + w;
        if (k < HID_DIM) {
            const float* wrow = Wp + (size_t)k * HIDH_DIM;
            float4 wr = *reinterpret_cast<const float4*>(wrow + lane * 4);
            float4 vb = *reinterpret_cast<const float4*>(wb + lane * 4);
            float4 vv = *reinterpret_cast<const float4*>(wv + lane * 4);
            float ub = dot4(wr, vb);
            float uv = dot4(wr, vv);
            #pragma unroll
            for (int off = 32; off > 0; off >>= 1) {
                ub += __shfl_down(ub, off, 64);
                uv += __shfl_down(uv, off, 64);
            }
            if (lane == 0) { u_bond[k] = ub; u_val[k] = uv; }
        }
    } else if (b < ZBLOCKS + 1 + UBLOCKS + GB) {
        int g = (b - ZBLOCKS - 1 - UBLOCKS) * 256 + t;
        if (g < G) {
            int idx = gen_idx[g];
            xgx[g] = x_t[3 * idx + 0];
            xgy[g] = x_t[3 * idx + 1];
            xgz[g] = x_t[3 * idx + 2];
        }
    } else {
        int base = ((b - ZBLOCKS - 1 - UBLOCKS - GB) * 256 + t) * 8;
        for (int k = 0; k < 8; ++k) {
            int i = base + k;
            if (i >= n) break;
            int lo = 0, hi = G - 1, g = -1;
            while (lo <= hi) {
                int mid = (lo + hi) >> 1;
                int v = gen_idx[mid];
                if (v == i) { g = mid; break; }
                if (v < i) lo = mid + 1; else hi = mid - 1;
            }
            mask[i] = (g >= 0) ? 1 : 0;
            if (g >= 0) gpos[i] = g;
        }
    }
}

// ---------------------------------------------------------------------------
// Gate kernel (ALONE — every resident wave streams H so HBM saturates on TLP):
// half-wave per row: 2 rows/wave, lanes l<32 -> rowA, l>=32 -> rowB.
// Each lane loads 4 independent float4 (its row's quarter-columns) -> 4 loads
// in flight; 5-step width-32 shuffle reduce; lanes 0 and 32 store.
__global__ __launch_bounds__(256) void gate_kernel(
        const float* __restrict__ H,
        const float* __restrict__ u_bond, const float* __restrict__ u_val,
        const float* __restrict__ cvals,
        float* __restrict__ bond_w, float* __restrict__ clash_w, int n) {
    int t = threadIdx.x, w = t >> 6, lane = t & 63;
    int half = lane >> 5, l = lane & 31;
    int row = blockIdx.x * 8 + w * 2 + half;
    if (row >= n) return;
    const float* h = H + (size_t)row * HID_DIM;
    int o = l * 4;
    float4 h0 = *reinterpret_cast<const float4*>(h + o);
    float4 h1 = *reinterpret_cast<const float4*>(h + o + 128);
    float4 h2 = *reinterpret_cast<const float4*>(h + o + 256);
    float4 h3 = *reinterpret_cast<const float4*>(h + o + 384);
    float4 ub0 = *reinterpret_cast<const float4*>(u_bond + o);
    float4 ub1 = *reinterpret_cast<const float4*>(u_bond + o + 128);
    float4 ub2 = *reinterpret_cast<const float4*>(u_bond + o + 256);
    float4 ub3 = *reinterpret_cast<const float4*>(u_bond + o + 384);
    float4 uv0 = *reinterpret_cast<const float4*>(u_val + o);
    float4 uv1 = *reinterpret_cast<const float4*>(u_val + o + 128);
    float4 uv2 = *reinterpret_cast<const float4*>(u_val + o + 256);
    float4 uv3 = *reinterpret_cast<const float4*>(u_val + o + 384);
    float sb = dot4(h0, ub0) + dot4(h1, ub1) + dot4(h2, ub2) + dot4(h3, ub3);
    float sv = dot4(h0, uv0) + dot4(h1, uv1) + dot4(h2, uv2) + dot4(h3, uv3);
    #pragma unroll
    for (int off = 16; off > 0; off >>= 1) {
        sb += __shfl_down(sb, off, 32);   // width=32: halves stay independent
        sv += __shfl_down(sv, off, 32);
    }
    if (l == 0) {
        bond_w[row]  = 1.f / (1.f + expf(-(sb + cvals[0])));
        clash_w[row] = 1.f / (1.f + expf(-(sv + cvals[1])));
    }
}

// ---------------------------------------------------------------------------
// Mega2: bond (latency-bound) + clash (VALU-bound) striped 4:2 per 6 blocks —
// good co-residents; neither needs HBM bandwidth.
__global__ __launch_bounds__(256) void bondclash_kernel(
        const unsigned int* __restrict__ ew, const int* __restrict__ flag_p,
        const float* __restrict__ x_t, const unsigned char* __restrict__ mask,
        const float* __restrict__ xgx, const float* __restrict__ xgy,
        const float* __restrict__ xgz,
        float* __restrict__ bond_corr,
        float4* __restrict__ partials,
        int n, int E, int G, int NBB, int NBC, int CXB) {
    __shared__ __align__(16) float sx[JC];
    __shared__ __align__(16) float sy[JC];
    __shared__ __align__(16) float sz[JC];
    int b = blockIdx.x, t = threadIdx.x;
    int stripe = b / 6, role = b - stripe * 6;

    if (role < 4) {
        // ---- bond scatter ----
        int eb = stripe * 4 + role;
        if (eb >= NBB) return;
        int e = eb * 256 + t;
        if (e >= E) return;
        int f = flag_p[0];
        int row, col;
        if (f) {  // int64 layout: low words at even word indices
            row = (int)ew[2 * (size_t)e];
            col = (int)ew[2 * ((size_t)E + e)];
        } else {  // int32 layout
            row = (int)ew[e];
            col = (int)ew[(size_t)E + e];
        }
        if ((unsigned)row >= (unsigned)n || (unsigned)col >= (unsigned)n) return;
        if (!(mask[row] | mask[col])) return;
        float dx = x_t[3 * row + 0] - x_t[3 * col + 0];
        float dy = x_t[3 * row + 1] - x_t[3 * col + 1];
        float dz = x_t[3 * row + 2] - x_t[3 * col + 2];
        float d2 = dx * dx + dy * dy + dz * dz;
        float dist = sqrtf(fmaxf(d2, 1e-24f)) + 1e-8f;
        float s = (dist - 1.5f) / (dist * dist);
        float fx = s * dx, fy = s * dy, fz = s * dz;
        atomicAdd(&bond_corr[3 * row + 0],  fx);
        atomicAdd(&bond_corr[3 * row + 1],  fy);
        atomicAdd(&bond_corr[3 * row + 2],  fz);
        atomicAdd(&bond_corr[3 * col + 0], -fx);
        atomicAdd(&bond_corr[3 * col + 1], -fy);
        atomicAdd(&bond_corr[3 * col + 2], -fz);
    } else {
        // ---- clash: branchless; float4 partial per (yc,i) ----
        int b2 = stripe * 2 + (role - 4);
        if (b2 >= NBC) return;
        int yc = b2 / CXB;
        int i  = (b2 - yc * CXB) * 256 + t;
        int j  = yc * JC + t;
        sx[t] = (j < G) ? xgx[j] : 1e30f;
        sy[t] = (j < G) ? xgy[j] : 1e30f;
        sz[t] = (j < G) ? xgz[j] : 1e30f;
        __syncthreads();
        if (i >= G) return;
        float xi = xgx[i], yi = xgy[i], zi = xgz[i];
        float csum = 0.f, cx = 0.f, cy = 0.f, cz = 0.f;
#define PROC(XS, YS, ZS) do {                                           \
            float dx = xi - (XS), dy = yi - (YS), dz = zi - (ZS);       \
            float d2 = fmaf(dx, dx, fmaf(dy, dy, dz * dz));             \
            float rm = __builtin_amdgcn_rsqf(d2);                       \
            float coef = fmaxf(fmaf(rm, rm, -rm), 0.0f);                \
            csum += coef;                                               \
            cx = fmaf(coef, (XS), cx);                                  \
            cy = fmaf(coef, (YS), cy);                                  \
            cz = fmaf(coef, (ZS), cz);                                  \
        } while (0)
        #pragma unroll 4
        for (int tt = 0; tt < JC; tt += 4) {
            float4 ax = *reinterpret_cast<const float4*>(&sx[tt]);
            float4 ay = *reinterpret_cast<const float4*>(&sy[tt]);
            float4 az = *reinterpret_cast<const float4*>(&sz[tt]);
            PROC(ax.x, ay.x, az.x);
            PROC(ax.y, ay.y, az.y);
            PROC(ax.z, ay.z, az.z);
            PROC(ax.w, ay.w, az.w);
        }
#undef PROC
        partials[(size_t)yc * G + i] = make_float4(csum, cx, cy, cz);
    }
}

// ---------------------------------------------------------------------------
// out = v_x - 0.1*bond_w*bond_corr - [mask] 0.05*clash_w*(xg*S - V),
// S,V summed from NYC coalesced float4 partials.
__global__ void final_kernel(const float* __restrict__ v_x,
                             const float* __restrict__ bond_w,
                             const float* __restrict__ clash_w,
                             const float* __restrict__ bond_corr,
                             const unsigned char* __restrict__ mask,
                             const int* __restrict__ gpos,
                             const float* __restrict__ xgx,
                             const float* __restrict__ xgy,
                             const float* __restrict__ xgz,
                             const float4* __restrict__ partials,
                             float* __restrict__ out, int n, int G, int NYC) {
    int i = blockIdx.x * blockDim.x + threadIdx.x;
    if (i >= n) return;
    float bw = 0.1f * bond_w[i];
    float ox = v_x[3 * i + 0] - bw * bond_corr[3 * i + 0];
    float oy = v_x[3 * i + 1] - bw * bond_corr[3 * i + 1];
    float oz = v_x[3 * i + 2] - bw * bond_corr[3 * i + 2];
    if (mask[i]) {
        int g = gpos[i];
        float s = 0.f, vx = 0.f, vy = 0.f, vz = 0.f;
        for (int yc = 0; yc < NYC; ++yc) {
            float4 p = partials[(size_t)yc * G + g];
            s += p.x; vx += p.y; vy += p.z; vz += p.w;
        }
        float cw = 0.05f * clash_w[i];
        ox -= cw * (xgx[g] * s - vx);
        oy -= cw * (xgy[g] * s - vy);
        oz -= cw * (xgz[g] * s - vz);
    }
    out[3 * i + 0] = ox;
    out[3 * i + 1] = oy;
    out[3 * i + 2] = oz;
}

// ---------------------------------------------------------------------------
extern "C" void kernel_launch(void* const* d_in, const int* in_sizes, int n_in,
                              void* d_out, int out_size, void* d_ws, size_t ws_size,
                              hipStream_t stream) {
    const float* v_x_raw = (const float*)d_in[0];
    const float* H       = (const float*)d_in[1];
    const float* x_t     = (const float*)d_in[2];
    const unsigned int* edges_w = (const unsigned int*)d_in[3];
    // d_in[4] = gen_mask (bool) — intentionally unused; rebuilt from gen_idx.
    const int* gen_idx   = (const int*)d_in[5];
    const float* W_proj  = (const float*)d_in[6];
    const float* b_proj  = (const float*)d_in[7];
    const float* w_bond  = (const float*)d_in[8];
    const float* b_bond  = (const float*)d_in[9];
    const float* w_val   = (const float*)d_in[10];
    const float* b_val   = (const float*)d_in[11];

    const int n = in_sizes[0] / 3;
    const int E = in_sizes[3] / 2;
    const int G = in_sizes[5];
    const int GB  = (G + 255) / 256;
    const int NYC = (G + JC - 1) / JC;   // clash y-chunks (32)

    char* ws = (char*)d_ws;
    // --- zeroed region (bond_corr only) ---
    float* bond_corr = (float*)(ws);
    size_t zbytes = (size_t)n * 12;
    size_t off = (zbytes + 15) & ~(size_t)15;
    int zcount = (int)(off / 16);
    // --- write-every-launch region ---
    unsigned char* mask = (unsigned char*)(ws + off); off += ((size_t)n + 15) & ~(size_t)15;
    int*   gpos    = (int*)(ws + off);                off += (size_t)n * 4;
    float* bond_w  = (float*)(ws + off);              off += (size_t)n * 4;
    float* clash_w = (float*)(ws + off);              off += (size_t)n * 4;
    float* u_bond  = (float*)(ws + off);              off += HID_DIM * 4;
    float* u_val   = (float*)(ws + off);              off += HID_DIM * 4;
    float* cvals   = (float*)(ws + off);              off += 16;
    int*   flag    = (int*)(ws + off);                off += 16;
    float* xgx     = (float*)(ws + off);              off += (size_t)G * 4;
    float* xgy     = (float*)(ws + off);              off += (size_t)G * 4;
    float* xgz     = (float*)(ws + off);              off += (size_t)G * 4;
    float4* partials = (float4*)(ws + off);           off += (size_t)NYC * G * 16;

    const int MB  = (n + 2047) / 2048;   // mask/gpos blocks (8 idx/thread)
    const int CXB = GB;                   // clash x-blocks
    const int NBC = CXB * NYC;            // clash blocks (1024)
    const int NBB = (E + 255) / 256;      // bond blocks (2048)

    // bond+clash stripes of 6: 4 bond + 2 clash
    int S = (NBB + 3) / 4;
    if ((NBC + 1) / 2 > S) S = (NBC + 1) / 2;

    prep_kernel<<<ZBLOCKS + 1 + UBLOCKS + GB + MB, 256, 0, stream>>>(
        edges_w, W_proj, b_proj, w_bond, b_bond, w_val, b_val,
        gen_idx, x_t, (float4*)ws, zcount,
        u_bond, u_val, cvals, flag, xgx, xgy, xgz, mask, gpos, n, G, GB);

    gate_kernel<<<(n + 7) / 8, 256, 0, stream>>>(
        H, u_bond, u_val, cvals, bond_w, clash_w, n);

    bondclash_kernel<<<S * 6, 256, 0, stream>>>(
        edges_w, flag, x_t, mask, xgx, xgy, xgz,
        bond_corr, partials, n, E, G, NBB, NBC, CXB);

    final_kernel<<<(n + 255) / 256, 256, 0, stream>>>(
        v_x_raw, bond_w, clash_w, bond_corr, mask, gpos,
        xgx, xgy, xgz, partials, (float*)d_out, n, G, NYC);
}

// Round 11
// 96.377 us; speedup vs baseline: 1.1793x; 1.1561x over previous
//
#include <hip/hip_runtime.h>
#include <math.h>

#define HID_DIM  512
#define HIDH_DIM 256
#define ZBLOCKS  125
#define UBLOCKS  128   // u-fold blocks: one wave per output k
#define JC       256   // clash j-tile (LDS-staged)

// ---------------------------------------------------------------------------
__device__ __forceinline__ float dot4(float4 a, float4 b) {
    return a.x * b.x + a.y * b.y + a.z * b.z + a.w * b.w;
}

// ---------------------------------------------------------------------------
// Fused prep:
//   [0,125)      : grid-stride zero of bond_corr
//   125          : edge-dtype probe + gen_idx regularity check + cvals reduce
//   [126,254)    : u-fold, one wave per k (coalesced float4 + butterfly)
//   [254,254+GB) : xg (SoA) gather
//   [..., +MB)   : mask/gpos via binary search over sorted gen_idx
__global__ __launch_bounds__(256) void prep_kernel(
        const unsigned int* __restrict__ ew,
        const float* __restrict__ Wp,  const float* __restrict__ bp,
        const float* __restrict__ wb,  const float* __restrict__ bb,
        const float* __restrict__ wv,  const float* __restrict__ bv,
        const int* __restrict__ gen_idx, const float* __restrict__ x_t,
        float4* __restrict__ zbase, int zcount,
        float* __restrict__ u_bond, float* __restrict__ u_val,
        float* __restrict__ cvals, int* __restrict__ flag,
        float* __restrict__ xgx, float* __restrict__ xgy, float* __restrict__ xgz,
        unsigned char* __restrict__ mask, int* __restrict__ gpos,
        int n, int G, int GB) {
    int b = blockIdx.x, t = threadIdx.x;
    if (b < ZBLOCKS) {
        const float4 z = make_float4(0.f, 0.f, 0.f, 0.f);
        for (int i = b * 256 + t; i < zcount; i += ZBLOCKS * 256) zbase[i] = z;
    } else if (b == ZBLOCKS) {
        if (t < 64) {  // wave 0: int64-vs-int32 edge layout probe
            unsigned int v = ew[2 * t + 1];
            unsigned long long bl = __ballot(v == 0u);
            if (t == 0) flag[0] = (bl == 0xFFFFFFFFFFFFFFFFULL) ? 1 : 0;
        }
        // gen_idx regularity: gen_idx[g] == g*step with pow2 step?
        __shared__ int ok;
        if (t == 0) ok = 1;
        __syncthreads();
        int step = n / G;
        int bad = (step <= 0) || ((step & (step - 1)) != 0) || (step * G != n);
        for (int g = t; g < G; g += 256)
            if (gen_idx[g] != g * step) bad = 1;
        if (bad) atomicAnd(&ok, 0);
        __syncthreads();
        if (t == 0) { flag[1] = ok; flag[2] = step - 1; }
        // cvals reduction
        __shared__ float s1[256], s2[256];
        float p1 = (t < HIDH_DIM) ? bp[t] * wb[t] : 0.f;
        float p2 = (t < HIDH_DIM) ? bp[t] * wv[t] : 0.f;
        s1[t] = p1; s2[t] = p2;
        __syncthreads();
        for (int s = 128; s > 0; s >>= 1) {
            if (t < s) { s1[t] += s1[t + s]; s2[t] += s2[t + s]; }
            __syncthreads();
        }
        if (t == 0) { cvals[0] = s1[0] + bb[0]; cvals[1] = s2[0] + bv[0]; }
    } else if (b < ZBLOCKS + 1 + UBLOCKS) {
        // one wave per output k: lanes cover the 256-wide dot coalesced
        int w = t >> 6, lane = t & 63;
        int k = (b - ZBLOCKS - 1) * 4 + w;
        if (k < HID_DIM) {
            const float* wrow = Wp + (size_t)k * HIDH_DIM;
            float4 wr = *reinterpret_cast<const float4*>(wrow + lane * 4);
            float4 vb = *reinterpret_cast<const float4*>(wb + lane * 4);
            float4 vv = *reinterpret_cast<const float4*>(wv + lane * 4);
            float ub = dot4(wr, vb);
            float uv = dot4(wr, vv);
            #pragma unroll
            for (int off = 32; off > 0; off >>= 1) {
                ub += __shfl_down(ub, off, 64);
                uv += __shfl_down(uv, off, 64);
            }
            if (lane == 0) { u_bond[k] = ub; u_val[k] = uv; }
        }
    } else if (b < ZBLOCKS + 1 + UBLOCKS + GB) {
        int g = (b - ZBLOCKS - 1 - UBLOCKS) * 256 + t;
        if (g < G) {
            int idx = gen_idx[g];
            xgx[g] = x_t[3 * idx + 0];
            xgy[g] = x_t[3 * idx + 1];
            xgz[g] = x_t[3 * idx + 2];
        }
    } else {
        int base = ((b - ZBLOCKS - 1 - UBLOCKS - GB) * 256 + t) * 8;
        for (int k = 0; k < 8; ++k) {
            int i = base + k;
            if (i >= n) break;
            int lo = 0, hi = G - 1, g = -1;
            while (lo <= hi) {
                int mid = (lo + hi) >> 1;
                int v = gen_idx[mid];
                if (v == i) { g = mid; break; }
                if (v < i) lo = mid + 1; else hi = mid - 1;
            }
            mask[i] = (g >= 0) ? 1 : 0;
            if (g >= 0) gpos[i] = g;
        }
    }
}

// ---------------------------------------------------------------------------
// Mega kernel v6 — stripe of 11: {0..7}->gate, {8,9}->bond, {10}->clash.
// Gate: half-wave per row, 4 H-loads/lane pinned in flight via empty asm.
__global__ __launch_bounds__(256) void mega_kernel(
        const float* __restrict__ H,
        const float* __restrict__ u_bond, const float* __restrict__ u_val,
        const float* __restrict__ cvals,
        const unsigned int* __restrict__ ew, const int* __restrict__ flag_p,
        const float* __restrict__ x_t, const unsigned char* __restrict__ mask,
        const float* __restrict__ xgx, const float* __restrict__ xgy,
        const float* __restrict__ xgz,
        float* __restrict__ bond_corr,
        float4* __restrict__ partials,
        float* __restrict__ bond_w, float* __restrict__ clash_w,
        int n, int E, int G, int NBG, int NBB, int NBC, int CXB) {
    __shared__ __align__(16) float sx[JC];
    __shared__ __align__(16) float sy[JC];
    __shared__ __align__(16) float sz[JC];
    int b = blockIdx.x, t = threadIdx.x;
    int stripe = b / 11, role = b - stripe * 11;

    if (role < 8) {
        // ---- gates: 8 rows/block, half-wave (32 lanes) per row, single pass ----
        int gb = stripe * 8 + role;
        if (gb >= NBG) return;
        int w = t >> 6, lane = t & 63;
        int half = lane >> 5, l = lane & 31;
        int row = gb * 8 + w * 2 + half;
        if (row >= n) return;
        const float* h = H + (size_t)row * HID_DIM;
        int o = l * 4;
        float4 h0 = *reinterpret_cast<const float4*>(h + o);
        float4 h1 = *reinterpret_cast<const float4*>(h + o + 128);
        float4 h2 = *reinterpret_cast<const float4*>(h + o + 256);
        float4 h3 = *reinterpret_cast<const float4*>(h + o + 384);
        // pin all 4 row-loads live before any consumption (defeats regalloc
        // serialization that collapsed ILP to 2 loads in r7/r9)
        asm volatile("" : "+v"(h0.x), "+v"(h0.y), "+v"(h0.z), "+v"(h0.w),
                          "+v"(h1.x), "+v"(h1.y), "+v"(h1.z), "+v"(h1.w),
                          "+v"(h2.x), "+v"(h2.y), "+v"(h2.z), "+v"(h2.w),
                          "+v"(h3.x), "+v"(h3.y), "+v"(h3.z), "+v"(h3.w));
        float4 ub0 = *reinterpret_cast<const float4*>(u_bond + o);
        float4 ub1 = *reinterpret_cast<const float4*>(u_bond + o + 128);
        float4 ub2 = *reinterpret_cast<const float4*>(u_bond + o + 256);
        float4 ub3 = *reinterpret_cast<const float4*>(u_bond + o + 384);
        float4 uv0 = *reinterpret_cast<const float4*>(u_val + o);
        float4 uv1 = *reinterpret_cast<const float4*>(u_val + o + 128);
        float4 uv2 = *reinterpret_cast<const float4*>(u_val + o + 256);
        float4 uv3 = *reinterpret_cast<const float4*>(u_val + o + 384);
        float sb = dot4(h0, ub0) + dot4(h1, ub1) + dot4(h2, ub2) + dot4(h3, ub3);
        float sv = dot4(h0, uv0) + dot4(h1, uv1) + dot4(h2, uv2) + dot4(h3, uv3);
        #pragma unroll
        for (int off = 16; off > 0; off >>= 1) {
            sb += __shfl_down(sb, off, 32);   // width=32: halves independent
            sv += __shfl_down(sv, off, 32);
        }
        if (l == 0) {
            bond_w[row]  = 1.f / (1.f + expf(-(sb + cvals[0])));
            clash_w[row] = 1.f / (1.f + expf(-(sv + cvals[1])));
        }
    } else if (role < 10) {
        // ---- bond scatter ----
        int eb = stripe * 2 + (role - 8);
        if (eb >= NBB) return;
        int e = eb * 256 + t;
        if (e >= E) return;
        int f = flag_p[0];
        int row, col;
        if (f) {  // int64 layout: low words at even word indices
            row = (int)ew[2 * (size_t)e];
            col = (int)ew[2 * ((size_t)E + e)];
        } else {  // int32 layout
            row = (int)ew[e];
            col = (int)ew[(size_t)E + e];
        }
        if ((unsigned)row >= (unsigned)n || (unsigned)col >= (unsigned)n) return;
        if (flag_p[1]) {  // regular gen_idx: gate test is pure ALU
            int m = flag_p[2];
            if (((row & m) != 0) && ((col & m) != 0)) return;
        } else {
            if (!(mask[row] | mask[col])) return;
        }
        float dx = x_t[3 * row + 0] - x_t[3 * col + 0];
        float dy = x_t[3 * row + 1] - x_t[3 * col + 1];
        float dz = x_t[3 * row + 2] - x_t[3 * col + 2];
        float d2 = dx * dx + dy * dy + dz * dz;
        float dist = sqrtf(fmaxf(d2, 1e-24f)) + 1e-8f;
        float s = (dist - 1.5f) / (dist * dist);
        float fx = s * dx, fy = s * dy, fz = s * dz;
        atomicAdd(&bond_corr[3 * row + 0],  fx);
        atomicAdd(&bond_corr[3 * row + 1],  fy);
        atomicAdd(&bond_corr[3 * row + 2],  fz);
        atomicAdd(&bond_corr[3 * col + 0], -fx);
        atomicAdd(&bond_corr[3 * col + 1], -fy);
        atomicAdd(&bond_corr[3 * col + 2], -fz);
    } else {
        // ---- clash: branchless; float4 partial per (yc,i) ----
        int b2 = stripe;
        if (b2 >= NBC) return;
        int yc = b2 / CXB;
        int i  = (b2 - yc * CXB) * 256 + t;
        int j  = yc * JC + t;
        sx[t] = (j < G) ? xgx[j] : 1e30f;
        sy[t] = (j < G) ? xgy[j] : 1e30f;
        sz[t] = (j < G) ? xgz[j] : 1e30f;
        __syncthreads();
        if (i >= G) return;
        float xi = xgx[i], yi = xgy[i], zi = xgz[i];
        float csum = 0.f, cx = 0.f, cy = 0.f, cz = 0.f;
#define PROC(XS, YS, ZS) do {                                           \
            float dx = xi - (XS), dy = yi - (YS), dz = zi - (ZS);       \
            float d2 = fmaf(dx, dx, fmaf(dy, dy, dz * dz));             \
            float rm = __builtin_amdgcn_rsqf(d2);                       \
            float coef = fmaxf(fmaf(rm, rm, -rm), 0.0f);                \
            csum += coef;                                               \
            cx = fmaf(coef, (XS), cx);                                  \
            cy = fmaf(coef, (YS), cy);                                  \
            cz = fmaf(coef, (ZS), cz);                                  \
        } while (0)
        #pragma unroll 4
        for (int tt = 0; tt < JC; tt += 4) {
            float4 ax = *reinterpret_cast<const float4*>(&sx[tt]);
            float4 ay = *reinterpret_cast<const float4*>(&sy[tt]);
            float4 az = *reinterpret_cast<const float4*>(&sz[tt]);
            PROC(ax.x, ay.x, az.x);
            PROC(ax.y, ay.y, az.y);
            PROC(ax.z, ay.z, az.z);
            PROC(ax.w, ay.w, az.w);
        }
#undef PROC
        partials[(size_t)yc * G + i] = make_float4(csum, cx, cy, cz);
    }
}

// ---------------------------------------------------------------------------
// out = v_x - 0.1*bond_w*bond_corr - [mask] 0.05*clash_w*(xg*S - V),
// S,V summed from NYC coalesced float4 partials.
__global__ void final_kernel(const float* __restrict__ v_x,
                             const float* __restrict__ bond_w,
                             const float* __restrict__ clash_w,
                             const float* __restrict__ bond_corr,
                             const unsigned char* __restrict__ mask,
                             const int* __restrict__ gpos,
                             const float* __restrict__ xgx,
                             const float* __restrict__ xgy,
                             const float* __restrict__ xgz,
                             const float4* __restrict__ partials,
                             float* __restrict__ out, int n, int G, int NYC) {
    int i = blockIdx.x * blockDim.x + threadIdx.x;
    if (i >= n) return;
    float bw = 0.1f * bond_w[i];
    float ox = v_x[3 * i + 0] - bw * bond_corr[3 * i + 0];
    float oy = v_x[3 * i + 1] - bw * bond_corr[3 * i + 1];
    float oz = v_x[3 * i + 2] - bw * bond_corr[3 * i + 2];
    if (mask[i]) {
        int g = gpos[i];
        float s = 0.f, vx = 0.f, vy = 0.f, vz = 0.f;
        for (int yc = 0; yc < NYC; ++yc) {
            float4 p = partials[(size_t)yc * G + g];
            s += p.x; vx += p.y; vy += p.z; vz += p.w;
        }
        float cw = 0.05f * clash_w[i];
        ox -= cw * (xgx[g] * s - vx);
        oy -= cw * (xgy[g] * s - vy);
        oz -= cw * (xgz[g] * s - vz);
    }
    out[3 * i + 0] = ox;
    out[3 * i + 1] = oy;
    out[3 * i + 2] = oz;
}

// ---------------------------------------------------------------------------
extern "C" void kernel_launch(void* const* d_in, const int* in_sizes, int n_in,
                              void* d_out, int out_size, void* d_ws, size_t ws_size,
                              hipStream_t stream) {
    const float* v_x_raw = (const float*)d_in[0];
    const float* H       = (const float*)d_in[1];
    const float* x_t     = (const float*)d_in[2];
    const unsigned int* edges_w = (const unsigned int*)d_in[3];
    // d_in[4] = gen_mask (bool) — intentionally unused; rebuilt from gen_idx.
    const int* gen_idx   = (const int*)d_in[5];
    const float* W_proj  = (const float*)d_in[6];
    const float* b_proj  = (const float*)d_in[7];
    const float* w_bond  = (const float*)d_in[8];
    const float* b_bond  = (const float*)d_in[9];
    const float* w_val   = (const float*)d_in[10];
    const float* b_val   = (const float*)d_in[11];

    const int n = in_sizes[0] / 3;
    const int E = in_sizes[3] / 2;
    const int G = in_sizes[5];
    const int GB  = (G + 255) / 256;
    const int NYC = (G + JC - 1) / JC;   // clash y-chunks (32)

    char* ws = (char*)d_ws;
    // --- zeroed region (bond_corr only) ---
    float* bond_corr = (float*)(ws);
    size_t zbytes = (size_t)n * 12;
    size_t off = (zbytes + 15) & ~(size_t)15;
    int zcount = (int)(off / 16);
    // --- write-every-launch region ---
    unsigned char* mask = (unsigned char*)(ws + off); off += ((size_t)n + 15) & ~(size_t)15;
    int*   gpos    = (int*)(ws + off);                off += (size_t)n * 4;
    float* bond_w  = (float*)(ws + off);              off += (size_t)n * 4;
    float* clash_w = (float*)(ws + off);              off += (size_t)n * 4;
    float* u_bond  = (float*)(ws + off);              off += HID_DIM * 4;
    float* u_val   = (float*)(ws + off);              off += HID_DIM * 4;
    float* cvals   = (float*)(ws + off);              off += 16;
    int*   flag    = (int*)(ws + off);                off += 16;
    float* xgx     = (float*)(ws + off);              off += (size_t)G * 4;
    float* xgy     = (float*)(ws + off);              off += (size_t)G * 4;
    float* xgz     = (float*)(ws + off);              off += (size_t)G * 4;
    float4* partials = (float4*)(ws + off);           off += (size_t)NYC * G * 16;

    const int MB  = (n + 2047) / 2048;   // mask/gpos blocks (8 idx/thread)
    const int CXB = GB;                   // clash x-blocks
    const int NBC = CXB * NYC;            // clash blocks (1024)
    const int NBG = (n + 7) / 8;          // gate blocks (8192)
    const int NBB = (E + 255) / 256;      // bond blocks (2048)

    // stripes of 11: 8 gate + 2 bond + 1 clash
    int S = (NBG + 7) / 8;
    if ((NBB + 1) / 2 > S) S = (NBB + 1) / 2;
    if (NBC > S) S = NBC;

    prep_kernel<<<ZBLOCKS + 1 + UBLOCKS + GB + MB, 256, 0, stream>>>(
        edges_w, W_proj, b_proj, w_bond, b_bond, w_val, b_val,
        gen_idx, x_t, (float4*)ws, zcount,
        u_bond, u_val, cvals, flag, xgx, xgy, xgz, mask, gpos, n, G, GB);

    mega_kernel<<<S * 11, 256, 0, stream>>>(
        H, u_bond, u_val, cvals, edges_w, flag, x_t, mask,
        xgx, xgy, xgz, bond_corr, partials, bond_w, clash_w,
        n, E, G, NBG, NBB, NBC, CXB);

    final_kernel<<<(n + 255) / 256, 256, 0, stream>>>(
        v_x_raw, bond_w, clash_w, bond_corr, mask, gpos,
        xgx, xgy, xgz, partials, (float*)d_out, n, G, NYC);
}

// Round 12
// 86.310 us; speedup vs baseline: 1.3168x; 1.1166x over previous
//
#include <hip/hip_runtime.h>
#include <math.h>

#define HID_DIM  512
#define HIDH_DIM 256
#define ZBLOCKS  125
#define UBLOCKS  128   // u-fold blocks: one wave per output k
#define JC       256   // clash j-tile (LDS-staged)

// ---------------------------------------------------------------------------
__device__ __forceinline__ float dot4(float4 a, float4 b) {
    return a.x * b.x + a.y * b.y + a.z * b.z + a.w * b.w;
}

// ---------------------------------------------------------------------------
// Fused prep:
//   [0,125)      : grid-stride zero of bond_corr
//   125          : edge-dtype probe + gen_idx regularity check + cvals reduce
//   [126,254)    : u-fold, one wave per k (coalesced float4 + butterfly)
//   [254,254+GB) : xg (SoA) gather
//   [..., +MB)   : mask/gpos — ONE lower-bound search per thread + walk
//                  (sorted gen_idx assumed, as in all prior rounds)
__global__ __launch_bounds__(256) void prep_kernel(
        const unsigned int* __restrict__ ew,
        const float* __restrict__ Wp,  const float* __restrict__ bp,
        const float* __restrict__ wb,  const float* __restrict__ bb,
        const float* __restrict__ wv,  const float* __restrict__ bv,
        const int* __restrict__ gen_idx, const float* __restrict__ x_t,
        float4* __restrict__ zbase, int zcount,
        float* __restrict__ u_bond, float* __restrict__ u_val,
        float* __restrict__ cvals, int* __restrict__ flag,
        float* __restrict__ xgx, float* __restrict__ xgy, float* __restrict__ xgz,
        unsigned char* __restrict__ mask, int* __restrict__ gpos,
        int n, int G, int GB) {
    int b = blockIdx.x, t = threadIdx.x;
    if (b < ZBLOCKS) {
        const float4 z = make_float4(0.f, 0.f, 0.f, 0.f);
        for (int i = b * 256 + t; i < zcount; i += ZBLOCKS * 256) zbase[i] = z;
    } else if (b == ZBLOCKS) {
        if (t < 64) {  // wave 0: int64-vs-int32 edge layout probe
            unsigned int v = ew[2 * t + 1];
            unsigned long long bl = __ballot(v == 0u);
            if (t == 0) flag[0] = (bl == 0xFFFFFFFFFFFFFFFFULL) ? 1 : 0;
        }
        // gen_idx regularity: gen_idx[g] == g*step with pow2 step?
        __shared__ int ok;
        if (t == 0) ok = 1;
        __syncthreads();
        int step = n / G;
        int bad = (step <= 0) || ((step & (step - 1)) != 0) || (step * G != n);
        for (int g = t; g < G; g += 256)
            if (gen_idx[g] != g * step) bad = 1;
        if (bad) atomicAnd(&ok, 0);
        __syncthreads();
        if (t == 0) { flag[1] = ok; flag[2] = step - 1; }
        // cvals reduction
        __shared__ float s1[256], s2[256];
        float p1 = (t < HIDH_DIM) ? bp[t] * wb[t] : 0.f;
        float p2 = (t < HIDH_DIM) ? bp[t] * wv[t] : 0.f;
        s1[t] = p1; s2[t] = p2;
        __syncthreads();
        for (int s = 128; s > 0; s >>= 1) {
            if (t < s) { s1[t] += s1[t + s]; s2[t] += s2[t + s]; }
            __syncthreads();
        }
        if (t == 0) { cvals[0] = s1[0] + bb[0]; cvals[1] = s2[0] + bv[0]; }
    } else if (b < ZBLOCKS + 1 + UBLOCKS) {
        // one wave per output k: lanes cover the 256-wide dot coalesced
        int w = t >> 6, lane = t & 63;
        int k = (b - ZBLOCKS - 1) * 4 + w;
        if (k < HID_DIM) {
            const float* wrow = Wp + (size_t)k * HIDH_DIM;
            float4 wr = *reinterpret_cast<const float4*>(wrow + lane * 4);
            float4 vb = *reinterpret_cast<const float4*>(wb + lane * 4);
            float4 vv = *reinterpret_cast<const float4*>(wv + lane * 4);
            float ub = dot4(wr, vb);
            float uv = dot4(wr, vv);
            #pragma unroll
            for (int off = 32; off > 0; off >>= 1) {
                ub += __shfl_down(ub, off, 64);
                uv += __shfl_down(uv, off, 64);
            }
            if (lane == 0) { u_bond[k] = ub; u_val[k] = uv; }
        }
    } else if (b < ZBLOCKS + 1 + UBLOCKS + GB) {
        int g = (b - ZBLOCKS - 1 - UBLOCKS) * 256 + t;
        if (g < G) {
            int idx = gen_idx[g];
            xgx[g] = x_t[3 * idx + 0];
            xgy[g] = x_t[3 * idx + 1];
            xgz[g] = x_t[3 * idx + 2];
        }
    } else {
        // mask/gpos: thread owns i in [base, base+8). One lower-bound search,
        // then walk forward over sorted gen_idx.
        int base = ((b - ZBLOCKS - 1 - UBLOCKS - GB) * 256 + t) * 8;
        if (base >= n) return;
        int hi8 = base + 8; if (hi8 > n) hi8 = n;
        // zero own range (owner-writes, no race)
        for (int i = base; i < hi8; ++i) mask[i] = 0;
        // lower bound: first g with gen_idx[g] >= base
        int lo = 0, hi = G;
        while (lo < hi) {
            int mid = (lo + hi) >> 1;
            if (gen_idx[mid] < base) lo = mid + 1; else hi = mid;
        }
        for (int g = lo; g < G; ++g) {
            int idx = gen_idx[g];
            if (idx >= hi8) break;
            mask[idx] = 1;
            gpos[idx] = g;
        }
    }
}

// ---------------------------------------------------------------------------
// Mega kernel v7 — stripe of 7: {0..3}->gate, {4,5}->bond, {6}->clash.
// Gate: 2 adjacent rows per half-wave; all 8 H-loads pinned in flight;
// each u-chunk load serves both rows.
__global__ __launch_bounds__(256) void mega_kernel(
        const float* __restrict__ H,
        const float* __restrict__ u_bond, const float* __restrict__ u_val,
        const float* __restrict__ cvals,
        const unsigned int* __restrict__ ew, const int* __restrict__ flag_p,
        const float* __restrict__ x_t, const unsigned char* __restrict__ mask,
        const float* __restrict__ xgx, const float* __restrict__ xgy,
        const float* __restrict__ xgz,
        float* __restrict__ bond_corr,
        float4* __restrict__ partials,
        float* __restrict__ bond_w, float* __restrict__ clash_w,
        int n, int E, int G, int NBG, int NBB, int NBC, int CXB) {
    __shared__ __align__(16) float sx[JC];
    __shared__ __align__(16) float sy[JC];
    __shared__ __align__(16) float sz[JC];
    int b = blockIdx.x, t = threadIdx.x;
    int stripe = b / 7, role = b - stripe * 7;

    if (role < 4) {
        // ---- gates: 16 rows/block, 2 rows per half-wave ----
        int gb = stripe * 4 + role;
        if (gb >= NBG) return;
        int w = t >> 6, lane = t & 63;
        int half = lane >> 5, l = lane & 31;
        int rowA = gb * 16 + (w * 2 + half) * 2;
        if (rowA >= n) return;
        bool vB = (rowA + 1 < n);
        const float* hA = H + (size_t)rowA * HID_DIM;
        const float* hB = hA + (vB ? HID_DIM : 0);
        int o = l * 4;
        float4 a0 = *reinterpret_cast<const float4*>(hA + o);
        float4 a1 = *reinterpret_cast<const float4*>(hA + o + 128);
        float4 a2 = *reinterpret_cast<const float4*>(hA + o + 256);
        float4 a3 = *reinterpret_cast<const float4*>(hA + o + 384);
        float4 b0 = *reinterpret_cast<const float4*>(hB + o);
        float4 b1 = *reinterpret_cast<const float4*>(hB + o + 128);
        float4 b2 = *reinterpret_cast<const float4*>(hB + o + 256);
        float4 b3 = *reinterpret_cast<const float4*>(hB + o + 384);
        // pin all 8 row-loads live before any consumption
        asm volatile("" : "+v"(a0.x), "+v"(a0.y), "+v"(a0.z), "+v"(a0.w),
                          "+v"(a1.x), "+v"(a1.y), "+v"(a1.z), "+v"(a1.w),
                          "+v"(a2.x), "+v"(a2.y), "+v"(a2.z), "+v"(a2.w),
                          "+v"(a3.x), "+v"(a3.y), "+v"(a3.z), "+v"(a3.w));
        asm volatile("" : "+v"(b0.x), "+v"(b0.y), "+v"(b0.z), "+v"(b0.w),
                          "+v"(b1.x), "+v"(b1.y), "+v"(b1.z), "+v"(b1.w),
                          "+v"(b2.x), "+v"(b2.y), "+v"(b2.z), "+v"(b2.w),
                          "+v"(b3.x), "+v"(b3.y), "+v"(b3.z), "+v"(b3.w));
        float4 ub0 = *reinterpret_cast<const float4*>(u_bond + o);
        float4 ub1 = *reinterpret_cast<const float4*>(u_bond + o + 128);
        float4 ub2 = *reinterpret_cast<const float4*>(u_bond + o + 256);
        float4 ub3 = *reinterpret_cast<const float4*>(u_bond + o + 384);
        float4 uv0 = *reinterpret_cast<const float4*>(u_val + o);
        float4 uv1 = *reinterpret_cast<const float4*>(u_val + o + 128);
        float4 uv2 = *reinterpret_cast<const float4*>(u_val + o + 256);
        float4 uv3 = *reinterpret_cast<const float4*>(u_val + o + 384);
        float sbA = dot4(a0, ub0) + dot4(a1, ub1) + dot4(a2, ub2) + dot4(a3, ub3);
        float svA = dot4(a0, uv0) + dot4(a1, uv1) + dot4(a2, uv2) + dot4(a3, uv3);
        float sbB = dot4(b0, ub0) + dot4(b1, ub1) + dot4(b2, ub2) + dot4(b3, ub3);
        float svB = dot4(b0, uv0) + dot4(b1, uv1) + dot4(b2, uv2) + dot4(b3, uv3);
        #pragma unroll
        for (int off = 16; off > 0; off >>= 1) {
            sbA += __shfl_down(sbA, off, 32);   // width=32: halves independent
            svA += __shfl_down(svA, off, 32);
            sbB += __shfl_down(sbB, off, 32);
            svB += __shfl_down(svB, off, 32);
        }
        if (l == 0) {
            bond_w[rowA]  = 1.f / (1.f + expf(-(sbA + cvals[0])));
            clash_w[rowA] = 1.f / (1.f + expf(-(svA + cvals[1])));
            if (vB) {
                bond_w[rowA + 1]  = 1.f / (1.f + expf(-(sbB + cvals[0])));
                clash_w[rowA + 1] = 1.f / (1.f + expf(-(svB + cvals[1])));
            }
        }
    } else if (role < 6) {
        // ---- bond scatter ----
        int eb = stripe * 2 + (role - 4);
        if (eb >= NBB) return;
        int e = eb * 256 + t;
        if (e >= E) return;
        int f = flag_p[0];
        int row, col;
        if (f) {  // int64 layout: low words at even word indices
            row = (int)ew[2 * (size_t)e];
            col = (int)ew[2 * ((size_t)E + e)];
        } else {  // int32 layout
            row = (int)ew[e];
            col = (int)ew[(size_t)E + e];
        }
        if ((unsigned)row >= (unsigned)n || (unsigned)col >= (unsigned)n) return;
        if (flag_p[1]) {  // regular gen_idx: gate test is pure ALU
            int m = flag_p[2];
            if (((row & m) != 0) && ((col & m) != 0)) return;
        } else {
            if (!(mask[row] | mask[col])) return;
        }
        float dx = x_t[3 * row + 0] - x_t[3 * col + 0];
        float dy = x_t[3 * row + 1] - x_t[3 * col + 1];
        float dz = x_t[3 * row + 2] - x_t[3 * col + 2];
        float d2 = dx * dx + dy * dy + dz * dz;
        float dist = sqrtf(fmaxf(d2, 1e-24f)) + 1e-8f;
        float s = (dist - 1.5f) / (dist * dist);
        float fx = s * dx, fy = s * dy, fz = s * dz;
        atomicAdd(&bond_corr[3 * row + 0],  fx);
        atomicAdd(&bond_corr[3 * row + 1],  fy);
        atomicAdd(&bond_corr[3 * row + 2],  fz);
        atomicAdd(&bond_corr[3 * col + 0], -fx);
        atomicAdd(&bond_corr[3 * col + 1], -fy);
        atomicAdd(&bond_corr[3 * col + 2], -fz);
    } else {
        // ---- clash: branchless; float4 partial per (yc,i) ----
        int b2 = stripe;
        if (b2 >= NBC) return;
        int yc = b2 / CXB;
        int i  = (b2 - yc * CXB) * 256 + t;
        int j  = yc * JC + t;
        sx[t] = (j < G) ? xgx[j] : 1e30f;
        sy[t] = (j < G) ? xgy[j] : 1e30f;
        sz[t] = (j < G) ? xgz[j] : 1e30f;
        __syncthreads();
        if (i >= G) return;
        float xi = xgx[i], yi = xgy[i], zi = xgz[i];
        float csum = 0.f, cx = 0.f, cy = 0.f, cz = 0.f;
#define PROC(XS, YS, ZS) do {                                           \
            float dx = xi - (XS), dy = yi - (YS), dz = zi - (ZS);       \
            float d2 = fmaf(dx, dx, fmaf(dy, dy, dz * dz));             \
            float rm = __builtin_amdgcn_rsqf(d2);                       \
            float coef = fmaxf(fmaf(rm, rm, -rm), 0.0f);                \
            csum += coef;                                               \
            cx = fmaf(coef, (XS), cx);                                  \
            cy = fmaf(coef, (YS), cy);                                  \
            cz = fmaf(coef, (ZS), cz);                                  \
        } while (0)
        #pragma unroll 4
        for (int tt = 0; tt < JC; tt += 4) {
            float4 ax = *reinterpret_cast<const float4*>(&sx[tt]);
            float4 ay = *reinterpret_cast<const float4*>(&sy[tt]);
            float4 az = *reinterpret_cast<const float4*>(&sz[tt]);
            PROC(ax.x, ay.x, az.x);
            PROC(ax.y, ay.y, az.y);
            PROC(ax.z, ay.z, az.z);
            PROC(ax.w, ay.w, az.w);
        }
#undef PROC
        partials[(size_t)yc * G + i] = make_float4(csum, cx, cy, cz);
    }
}

// ---------------------------------------------------------------------------
// out = v_x - 0.1*bond_w*bond_corr - [mask] 0.05*clash_w*(xg*S - V),
// S,V summed from NYC coalesced float4 partials.
__global__ void final_kernel(const float* __restrict__ v_x,
                             const float* __restrict__ bond_w,
                             const float* __restrict__ clash_w,
                             const float* __restrict__ bond_corr,
                             const unsigned char* __restrict__ mask,
                             const int* __restrict__ gpos,
                             const float* __restrict__ xgx,
                             const float* __restrict__ xgy,
                             const float* __restrict__ xgz,
                             const float4* __restrict__ partials,
                             float* __restrict__ out, int n, int G, int NYC) {
    int i = blockIdx.x * blockDim.x + threadIdx.x;
    if (i >= n) return;
    float bw = 0.1f * bond_w[i];
    float ox = v_x[3 * i + 0] - bw * bond_corr[3 * i + 0];
    float oy = v_x[3 * i + 1] - bw * bond_corr[3 * i + 1];
    float oz = v_x[3 * i + 2] - bw * bond_corr[3 * i + 2];
    if (mask[i]) {
        int g = gpos[i];
        float s = 0.f, vx = 0.f, vy = 0.f, vz = 0.f;
        for (int yc = 0; yc < NYC; ++yc) {
            float4 p = partials[(size_t)yc * G + g];
            s += p.x; vx += p.y; vy += p.z; vz += p.w;
        }
        float cw = 0.05f * clash_w[i];
        ox -= cw * (xgx[g] * s - vx);
        oy -= cw * (xgy[g] * s - vy);
        oz -= cw * (xgz[g] * s - vz);
    }
    out[3 * i + 0] = ox;
    out[3 * i + 1] = oy;
    out[3 * i + 2] = oz;
}

// ---------------------------------------------------------------------------
extern "C" void kernel_launch(void* const* d_in, const int* in_sizes, int n_in,
                              void* d_out, int out_size, void* d_ws, size_t ws_size,
                              hipStream_t stream) {
    const float* v_x_raw = (const float*)d_in[0];
    const float* H       = (const float*)d_in[1];
    const float* x_t     = (const float*)d_in[2];
    const unsigned int* edges_w = (const unsigned int*)d_in[3];
    // d_in[4] = gen_mask (bool) — intentionally unused; rebuilt from gen_idx.
    const int* gen_idx   = (const int*)d_in[5];
    const float* W_proj  = (const float*)d_in[6];
    const float* b_proj  = (const float*)d_in[7];
    const float* w_bond  = (const float*)d_in[8];
    const float* b_bond  = (const float*)d_in[9];
    const float* w_val   = (const float*)d_in[10];
    const float* b_val   = (const float*)d_in[11];

    const int n = in_sizes[0] / 3;
    const int E = in_sizes[3] / 2;
    const int G = in_sizes[5];
    const int GB  = (G + 255) / 256;
    const int NYC = (G + JC - 1) / JC;   // clash y-chunks (32)

    char* ws = (char*)d_ws;
    // --- zeroed region (bond_corr only) ---
    float* bond_corr = (float*)(ws);
    size_t zbytes = (size_t)n * 12;
    size_t off = (zbytes + 15) & ~(size_t)15;
    int zcount = (int)(off / 16);
    // --- write-every-launch region ---
    unsigned char* mask = (unsigned char*)(ws + off); off += ((size_t)n + 15) & ~(size_t)15;
    int*   gpos    = (int*)(ws + off);                off += (size_t)n * 4;
    float* bond_w  = (float*)(ws + off);              off += (size_t)n * 4;
    float* clash_w = (float*)(ws + off);              off += (size_t)n * 4;
    float* u_bond  = (float*)(ws + off);              off += HID_DIM * 4;
    float* u_val   = (float*)(ws + off);              off += HID_DIM * 4;
    float* cvals   = (float*)(ws + off);              off += 16;
    int*   flag    = (int*)(ws + off);                off += 16;
    float* xgx     = (float*)(ws + off);              off += (size_t)G * 4;
    float* xgy     = (float*)(ws + off);              off += (size_t)G * 4;
    float* xgz     = (float*)(ws + off);              off += (size_t)G * 4;
    float4* partials = (float4*)(ws + off);           off += (size_t)NYC * G * 16;

    const int MB  = (n + 2047) / 2048;   // mask/gpos blocks (8 idx/thread)
    const int CXB = GB;                   // clash x-blocks
    const int NBC = CXB * NYC;            // clash blocks (1024)
    const int NBG = (n + 15) / 16;        // gate blocks (4096, 16 rows each)
    const int NBB = (E + 255) / 256;      // bond blocks (2048)

    // stripes of 7: 4 gate + 2 bond + 1 clash
    int S = (NBG + 3) / 4;
    if ((NBB + 1) / 2 > S) S = (NBB + 1) / 2;
    if (NBC > S) S = NBC;

    prep_kernel<<<ZBLOCKS + 1 + UBLOCKS + GB + MB, 256, 0, stream>>>(
        edges_w, W_proj, b_proj, w_bond, b_bond, w_val, b_val,
        gen_idx, x_t, (float4*)ws, zcount,
        u_bond, u_val, cvals, flag, xgx, xgy, xgz, mask, gpos, n, G, GB);

    mega_kernel<<<S * 7, 256, 0, stream>>>(
        H, u_bond, u_val, cvals, edges_w, flag, x_t, mask,
        xgx, xgy, xgz, bond_corr, partials, bond_w, clash_w,
        n, E, G, NBG, NBB, NBC, CXB);

    final_kernel<<<(n + 255) / 256, 256, 0, stream>>>(
        v_x_raw, bond_w, clash_w, bond_corr, mask, gpos,
        xgx, xgy, xgz, partials, (float*)d_out, n, G, NYC);
}